// Round 6
// baseline (119.001 us; speedup 1.0000x reference)
//
#include <hip/hip_runtime.h>

// Problem constants (StochPool: B=64, N_PER=1024, D=256, K=64, DEG=16)
#define NN 65536           // total nodes
#define DD 256             // feature dim
#define KK 64              // pools per graph
#define NPG 1024           // nodes per graph

// d_out layout (flat float32, outputs concatenated in return order)
#define OUT_OFF   0          // (4096, 256)
#define ADJ_OFF   1048576    // (64, 64, 64)
#define LINK_OFF  1310720    // scalar
#define ENT_OFF   1310721    // scalar
#define BATCH_OFF 1310722    // (4096,) as float
#define BPTR_OFF  1314818    // (65,) as float

// ws layout (bytes)
#define WS_ASSIGN 0          // int32 x 65536
#define WS_S1     262144     // float x 65536
#define WS_C      524288     // float x 4096   (StS diagonal accum)
#define WS_SQA    540672     // float x 64
#define WS_CROSS  540928     // float x 64
#define WS_ENT    541184     // float x 1
#define WS_SORT   1048576    // int32 x 65536 (node ids sorted by cluster, per graph)
#define WS_GOFF   1310720    // int32 x 64*65 (per-graph bin offsets)
#define WS_ADJP   1331200    // float x 256*4096 (per-block adjacency partials, 4 MB)
#define WS_NEED   (WS_ADJP + 256 * 4096 * 4)

// ---------------------------------------------------------------------------
// Kernel 1: logits GEMM + softmax stats, lane = node, W via SGPR.
// 1024 blocks x 256 threads (4 waves); block owns 64 consecutive nodes.
// Wave w: kh = w&1 (k-half, 32 k's), dh = w>>1 (d-half, 128 d's).
// acc[32] per lane = logits of node `lane` for its k-half (d-half partial).
// x: staged in LDS with +1-word pad (stride 131 words -> 2-way bank alias,
// free); 1 ds_read_b128 per 128 FMAs. W[d][k]: wave-uniform address ->
// s_load (scalar pipe), FMA = v_fmac vacc, sW, vx. LDS pipe ~60 ops/wave
// (vs ~2600 in the tiled version). 4096 waves = 4/SIMD.
// ---------------------------------------------------------------------------
__global__ __launch_bounds__(256, 4) void pool_assign_kernel(
    const float* __restrict__ x, const float* __restrict__ Wm,
    const float* __restrict__ bvec, const float* __restrict__ gum,
    int* __restrict__ assign, float* __restrict__ s1g,
    float* __restrict__ c_acc, float* __restrict__ ent_acc)
{
  __shared__ float lds_x[64 * 131];   // [row][slot(2)*65] (+1 pad word) 33.5KB
  __shared__ float comb[2 * 64 * 33]; // [kh][lane][33] d-combine buffer 16.9KB
  __shared__ float excm[2][64];
  __shared__ int   exca[2][64];
  __shared__ float excs[2][64];
  const int t    = threadIdx.x;
  const int lane = t & 63;
  const int kh   = __builtin_amdgcn_readfirstlane((t >> 6) & 1);
  const int dh   = __builtin_amdgcn_readfirstlane(t >> 7);
  const int nb0  = blockIdx.x << 6;   // 64 nodes per block
  const int node = nb0 + lane;

  float acc[32];
  #pragma unroll
  for (int j = 0; j < 32; ++j) acc[j] = 0.f;

  for (int r = 0; r < 2; ++r) {
    // stage rows 0..63, slot s = chunk s*2+r (dh0 uses chunks 0/1, dh1 2/3)
    #pragma unroll
    for (int i = 0; i < 8; ++i) {
      int idx  = t + (i << 8);        // 0..2047
      int col4 = idx & 15;
      int slot = (idx >> 4) & 1;
      int row  = idx >> 5;
      float4 v = *(const float4*)(x + (size_t)(nb0 + row) * DD
                                    + (((slot << 1) + r) << 6) + (col4 << 2));
      *(float4*)(&lds_x[row * 131 + slot * 65 + (col4 << 2)]) = v;
    }
    __syncthreads();
    // this wave's 64-d chunk: d0 = (dh*2 + r)*64 ; W base wave-uniform
    const float* wbase = Wm + (size_t)(((dh << 1) + r) << 6) * 64 + kh * 32;
    #pragma unroll 2
    for (int q = 0; q < 16; ++q) {
      float4 xv = *(const float4*)(&lds_x[lane * 131 + dh * 65 + (q << 2)]);
      const float* xp = (const float*)&xv;
      #pragma unroll
      for (int m = 0; m < 4; ++m) {
        const float* wr = wbase + (size_t)((q << 2) + m) * 64;  // uniform
        float xs = xp[m];
        #pragma unroll
        for (int j = 0; j < 32; ++j)
          acc[j] = fmaf(xs, wr[j], acc[j]);
      }
    }
    __syncthreads();
  }

  // d-combine: dh1 waves publish partial logits, dh0 waves accumulate
  if (dh == 1) {
    #pragma unroll
    for (int j = 0; j < 32; ++j) comb[(kh * 64 + lane) * 33 + j] = acc[j];
  }
  __syncthreads();
  float m = -3.4e38f; int a = 0;
  if (dh == 0) {
    const float* gp = gum + (size_t)node * KK + kh * 32;
    const float* bp = bvec + kh * 32;                    // uniform -> SGPR
    #pragma unroll
    for (int jq = 0; jq < 8; ++jq) {
      float4 g = *(const float4*)(gp + (jq << 2));
      acc[jq * 4 + 0] += comb[(kh * 64 + lane) * 33 + jq * 4 + 0] + bp[jq * 4 + 0] + g.x;
      acc[jq * 4 + 1] += comb[(kh * 64 + lane) * 33 + jq * 4 + 1] + bp[jq * 4 + 1] + g.y;
      acc[jq * 4 + 2] += comb[(kh * 64 + lane) * 33 + jq * 4 + 2] + bp[jq * 4 + 2] + g.z;
      acc[jq * 4 + 3] += comb[(kh * 64 + lane) * 33 + jq * 4 + 3] + bp[jq * 4 + 3] + g.w;
    }
    // in-lane tournament over this k-half (strict > keeps first max)
    m = acc[0]; a = kh * 32;
    #pragma unroll
    for (int j = 1; j < 32; ++j)
      if (acc[j] > m) { m = acc[j]; a = kh * 32 + j; }
    excm[kh][lane] = m; exca[kh][lane] = a;
  }
  __syncthreads();
  float ls = 0.f; int astar = 0;
  if (dh == 0) {
    float mo = excm[kh ^ 1][lane]; int ao = exca[kh ^ 1][lane];
    bool other = (mo > m) || (mo == m && ao < a);    // ties -> lower k
    float mstar = other ? mo : m;
    astar = other ? ao : a;
    #pragma unroll
    for (int j = 0; j < 32; ++j) ls += expf(acc[j] - mstar);
    excs[kh][lane] = ls;
  }
  __syncthreads();
  if (t < 64) {                                      // wave 0 (kh0,dh0)
    float total = ls + excs[1][lane];
    float p  = 1.0f / total;                         // softmax value at argmax
    float s1 = (1.0f - p) + p;                       // straight-through (≈1)
    assign[node] = astar;
    s1g[node]    = s1;
    int g = node >> 10;
    atomicAdd(&c_acc[(g << 6) + astar], s1 * s1);
    float ent = -s1 * logf(s1 + 1e-15f);             // non-argmax terms = 0
    #pragma unroll
    for (int off = 32; off; off >>= 1) ent += __shfl_down(ent, off, 64);
    if (lane == 0) atomicAdd(ent_acc, ent);
  }
}

// ---------------------------------------------------------------------------
// Kernel 2a: per-graph counting sort of nodes by cluster.
// 64 blocks (one per graph) x 256 threads x 4 nodes.
// ---------------------------------------------------------------------------
__global__ __launch_bounds__(256) void sort_kernel(
    const int* __restrict__ assign, int* __restrict__ sorted,
    int* __restrict__ goff)
{
  __shared__ int hist[64];
  __shared__ int offs[65];
  __shared__ int cursor[64];
  const int t = threadIdx.x;
  const int g = blockIdx.x;
  const int n0 = g << 10;
  if (t < 64) hist[t] = 0;
  __syncthreads();
  int4 av = ((const int4*)(assign + n0))[t];   // nodes t*4 .. t*4+3
  atomicAdd(&hist[av.x], 1);
  atomicAdd(&hist[av.y], 1);
  atomicAdd(&hist[av.z], 1);
  atomicAdd(&hist[av.w], 1);
  __syncthreads();
  if (t == 0) {
    int s = 0;
    #pragma unroll
    for (int k = 0; k < 64; ++k) { offs[k] = s; s += hist[k]; }
    offs[64] = s;   // = 1024
  }
  __syncthreads();
  if (t < 64) cursor[t] = offs[t];
  if (t < 65) goff[g * 65 + t] = offs[t];
  __syncthreads();
  int p;
  p = atomicAdd(&cursor[av.x], 1); sorted[n0 + p] = n0 + t * 4 + 0;
  p = atomicAdd(&cursor[av.y], 1); sorted[n0 + p] = n0 + t * 4 + 1;
  p = atomicAdd(&cursor[av.z], 1); sorted[n0 + p] = n0 + t * 4 + 2;
  p = atomicAdd(&cursor[av.w], 1); sorted[n0 + p] = n0 + t * 4 + 3;
}

// ---------------------------------------------------------------------------
// Kernel 2b: pooled features via dense gather.
// 4096 blocks = (graph g, cluster k) x 256 threads (one output dim each).
// ---------------------------------------------------------------------------
__global__ __launch_bounds__(256, 8) void gather_kernel(
    const float* __restrict__ x, const float* __restrict__ s1,
    const int* __restrict__ sorted, const int* __restrict__ goff,
    float* __restrict__ out)
{
  const int t = threadIdx.x;
  const int g = blockIdx.x >> 6;
  const int k = blockIdx.x & 63;
  const int o0 = goff[g * 65 + k];
  const int o1 = goff[g * 65 + k + 1];
  const int* sp = sorted + (g << 10);
  float sum = 0.f;
  int i = o0;
  for (; i + 4 <= o1; i += 4) {
    int n0 = sp[i], n1 = sp[i + 1], n2 = sp[i + 2], n3 = sp[i + 3];
    float w0 = s1[n0], w1 = s1[n1], w2 = s1[n2], w3 = s1[n3];
    float x0 = x[(size_t)n0 * DD + t];
    float x1 = x[(size_t)n1 * DD + t];
    float x2 = x[(size_t)n2 * DD + t];
    float x3 = x[(size_t)n3 * DD + t];
    sum += w0 * x0 + w1 * x1 + w2 * x2 + w3 * x3;
  }
  for (; i < o1; ++i) {
    int n = sp[i];
    sum += s1[n] * x[(size_t)n * DD + t];
  }
  out[((size_t)(g * 64 + k)) * DD + t] = sum;
}

// ---------------------------------------------------------------------------
// Kernel 3: edges -> per-block LDS adjacency, plain-stored partials in ws.
// 256 blocks (4 per graph) x 1024 threads x 4 edges.
// ---------------------------------------------------------------------------
__global__ __launch_bounds__(1024, 2) void edge_kernel(
    const int* __restrict__ src, const int* __restrict__ dst,
    const float* __restrict__ ew, const int* __restrict__ assign,
    const float* __restrict__ s1, float* __restrict__ adj_partial,
    float* __restrict__ sqA, float* __restrict__ crossA)
{
  __shared__ float adj[4096];           // 64x64 pooled adjacency (partial)
  const int t   = threadIdx.x;
  const int blk = blockIdx.x;
  const int g   = blk >> 2;
  #pragma unroll
  for (int i = 0; i < 4; ++i) adj[i * 1024 + t] = 0.f;
  __syncthreads();
  const int e0 = (g << 14) + ((blk & 3) << 12);   // 4096 edges per block
  float sq = 0.f, cr = 0.f;
  #pragma unroll
  for (int i = 0; i < 4; ++i) {
    int e = e0 + i * 1024 + t;
    int u = src[e], v = dst[e];
    float w = ew[e];
    int au = assign[u], av = assign[v];
    float contrib = w * s1[u] * s1[v];
    atomicAdd(&adj[au * 64 + av], contrib);   // ds_add_f32
    sq += w * w;
    if (au == av) cr += contrib;
  }
  #pragma unroll
  for (int off = 32; off; off >>= 1) {
    sq += __shfl_down(sq, off, 64);
    cr += __shfl_down(cr, off, 64);
  }
  if ((t & 63) == 0) {
    atomicAdd(&sqA[g], sq);
    atomicAdd(&crossA[g], cr);
  }
  __syncthreads();
  float* pp = adj_partial + (size_t)blk * 4096;
  #pragma unroll
  for (int i = 0; i < 4; ++i) pp[i * 1024 + t] = adj[i * 1024 + t];
}

// Combine 4 partials per graph -> out_adj (plain stores, fully overwrites).
__global__ __launch_bounds__(1024) void adj_combine_kernel(
    const float* __restrict__ adj_partial, float* __restrict__ out_adj)
{
  int idx = blockIdx.x * 1024 + threadIdx.x;   // 262144 cells
  int g = idx >> 12;
  int cell = idx & 4095;
  const float* p = adj_partial + ((size_t)(g * 4)) * 4096 + cell;
  out_adj[idx] = p[0] + p[4096] + p[8192] + p[12288];
}

// Fallback (small ws): global-atomic combine, needs out_adj pre-zeroed.
__global__ __launch_bounds__(1024, 2) void edge_kernel_atomic(
    const int* __restrict__ src, const int* __restrict__ dst,
    const float* __restrict__ ew, const int* __restrict__ assign,
    const float* __restrict__ s1, float* __restrict__ out_adj,
    float* __restrict__ sqA, float* __restrict__ crossA)
{
  __shared__ float adj[4096];
  const int t   = threadIdx.x;
  const int blk = blockIdx.x;
  const int g   = blk >> 2;
  #pragma unroll
  for (int i = 0; i < 4; ++i) adj[i * 1024 + t] = 0.f;
  __syncthreads();
  const int e0 = (g << 14) + ((blk & 3) << 12);
  float sq = 0.f, cr = 0.f;
  #pragma unroll
  for (int i = 0; i < 4; ++i) {
    int e = e0 + i * 1024 + t;
    int u = src[e], v = dst[e];
    float w = ew[e];
    int au = assign[u], av = assign[v];
    float contrib = w * s1[u] * s1[v];
    atomicAdd(&adj[au * 64 + av], contrib);
    sq += w * w;
    if (au == av) cr += contrib;
  }
  #pragma unroll
  for (int off = 32; off; off >>= 1) {
    sq += __shfl_down(sq, off, 64);
    cr += __shfl_down(cr, off, 64);
  }
  if ((t & 63) == 0) {
    atomicAdd(&sqA[g], sq);
    atomicAdd(&crossA[g], cr);
  }
  __syncthreads();
  float* adjg = out_adj + (size_t)g * 4096;
  #pragma unroll
  for (int i = 0; i < 4; ++i)
    atomicAdd(&adjg[i * 1024 + t], adj[i * 1024 + t]);
}

// ---------------------------------------------------------------------------
// Kernel 4: link/entropy scalars + batch / batch_ptr tails.
// ---------------------------------------------------------------------------
__global__ __launch_bounds__(256) void finalize_kernel(
    const float* __restrict__ c, const float* __restrict__ sqA,
    const float* __restrict__ crossA, const float* __restrict__ ent_acc,
    float* __restrict__ out)
{
  const int t = threadIdx.x;
  float link = 0.f;
  if (t < 64) {
    const float* cg = c + t * 64;
    float ssq = 0.f;
    #pragma unroll
    for (int k = 0; k < 64; ++k) ssq += cg[k] * cg[k];
    float val = sqA[t] - 2.0f * crossA[t] + ssq;
    link = sqrtf(fmaxf(val, 0.f)) / 16384.0f;   // e_per = 16384
  }
  #pragma unroll
  for (int off = 32; off; off >>= 1) link += __shfl_down(link, off, 64);
  if (t == 0) {
    out[LINK_OFF] = link / 64.0f;
    out[ENT_OFF]  = ent_acc[0] / (float)NN;
  }
  for (int r = t; r < 4096; r += 256) out[BATCH_OFF + r] = (float)(r >> 6);
  for (int i = t; i < 65; i += 256)   out[BPTR_OFF + i]  = (float)(i << 6);
}

extern "C" void kernel_launch(void* const* d_in, const int* in_sizes, int n_in,
                              void* d_out, int out_size, void* d_ws, size_t ws_size,
                              hipStream_t stream) {
  const float* x    = (const float*)d_in[0];
  const float* ew   = (const float*)d_in[1];
  const float* Wm   = (const float*)d_in[2];
  const float* bvec = (const float*)d_in[3];
  const float* gum  = (const float*)d_in[4];
  const int*   eidx = (const int*)d_in[5];
  float* out = (float*)d_out;
  char*  ws  = (char*)d_ws;

  int*   assign = (int*)(ws + WS_ASSIGN);
  float* s1     = (float*)(ws + WS_S1);
  float* c      = (float*)(ws + WS_C);
  float* sqA    = (float*)(ws + WS_SQA);
  float* crossA = (float*)(ws + WS_CROSS);
  float* entacc = (float*)(ws + WS_ENT);
  int*   sorted = (int*)(ws + WS_SORT);
  int*   goff   = (int*)(ws + WS_GOFF);
  float* adjp   = (float*)(ws + WS_ADJP);

  const int E = in_sizes[1];   // 1048576

  // zero the small atomic accumulators (c, sqA, crossA, ent)
  hipMemsetAsync(ws + WS_C, 0, (WS_ENT + 4) - WS_C, stream);

  pool_assign_kernel<<<1024, 256, 0, stream>>>(x, Wm, bvec, gum, assign, s1, c, entacc);
  sort_kernel<<<64, 256, 0, stream>>>(assign, sorted, goff);
  gather_kernel<<<4096, 256, 0, stream>>>(x, s1, sorted, goff, out + OUT_OFF);
  if (ws_size >= (size_t)WS_NEED) {
    edge_kernel<<<256, 1024, 0, stream>>>(eidx, eidx + E, ew, assign, s1,
                                          adjp, sqA, crossA);
    adj_combine_kernel<<<256, 1024, 0, stream>>>(adjp, out + ADJ_OFF);
  } else {
    hipMemsetAsync(out + ADJ_OFF, 0, (size_t)64 * 4096 * 4, stream);
    edge_kernel_atomic<<<256, 1024, 0, stream>>>(eidx, eidx + E, ew, assign, s1,
                                                 out + ADJ_OFF, sqA, crossA);
  }
  finalize_kernel<<<1, 256, 0, stream>>>(c, sqA, crossA, entacc, out);
}

// Round 7
// 91.939 us; speedup vs baseline: 1.2944x; 1.2944x over previous
//
#include <hip/hip_runtime.h>

// Problem constants (StochPool: B=64, N_PER=1024, D=256, K=64, DEG=16)
#define NN 65536           // total nodes
#define DD 256             // feature dim
#define KK 64              // pools per graph
#define NPG 1024           // nodes per graph

// d_out layout (flat float32, outputs concatenated in return order)
#define OUT_OFF   0          // (4096, 256)
#define ADJ_OFF   1048576    // (64, 64, 64)
#define LINK_OFF  1310720    // scalar
#define ENT_OFF   1310721    // scalar
#define BATCH_OFF 1310722    // (4096,) as float
#define BPTR_OFF  1314818    // (65,) as float

// ws layout (bytes)
#define WS_ASSIGN 0          // int32 x 65536
#define WS_S1     262144     // float x 65536
#define WS_C      524288     // float x 4096   (StS diagonal accum)
#define WS_SQA    540672     // float x 64
#define WS_CROSS  540928     // float x 64
#define WS_ENT    541184     // float x 1
#define WS_SORT   1048576    // int32 x 65536 (node ids sorted by cluster, per graph)
#define WS_GOFF   1310720    // int32 x 64*65 (per-graph bin offsets)
#define WS_ADJP   1331200    // float x 256*4096 (per-block adjacency partials, 4 MB)
#define WS_NEED   (WS_ADJP + 256 * 4096 * 4)

typedef __bf16 bf16x8 __attribute__((ext_vector_type(8)));
typedef unsigned short u16x8 __attribute__((ext_vector_type(8)));
typedef float f32x4 __attribute__((ext_vector_type(4)));

// f32 -> bf16 with round-to-nearest-even
static __device__ __forceinline__ unsigned short f2bf(float f) {
  unsigned int u = __float_as_uint(f);
  return (unsigned short)((u + 0x7fffu + ((u >> 16) & 1u)) >> 16);
}

// ---------------------------------------------------------------------------
// Kernel 1: logits GEMM via bf16 MFMA + in-register argmax/softmax.
// 1024 blocks x 256 threads (4 waves); block owns 64 consecutive nodes,
// wave wv owns nodes [nb0+16*wv, +16). Per wave: 4 N-tiles of
// mfma_f32_16x16x32_bf16 x 8 K-steps (K=256).
// A-frags: lane reads x[nb0+16wv+(l&15)][kb*32+(l>>4)*8 ..+7] straight from
// global f32 (4-lane groups form 128B contiguous; x read exactly once),
// converted bf16 in-register, kept across N-tiles.
// B-frags: W (64KB, L2-hot) transposed+converted per block into LDS
// Wt[64 k][264 d] bf16 (pad -> ~2-way bank alias); 1 ds_read_b128 each.
// C-layout (m89): col=lane&15, row=(lane>>4)*4+reg -> softmax per row =
// in-lane over 4 N-tiles + 4x __shfl_xor over the 16-lane group.
// ---------------------------------------------------------------------------
__global__ __launch_bounds__(256, 4) void pool_assign_kernel(
    const float* __restrict__ x, const float* __restrict__ Wm,
    const float* __restrict__ bvec, const float* __restrict__ gum,
    int* __restrict__ assign, float* __restrict__ s1g,
    float* __restrict__ c_acc, float* __restrict__ ent_acc)
{
  __shared__ unsigned short lds_wt[64 * 264];   // Wt[k][d] bf16, 33 KB
  __shared__ float esum[4];
  const int t    = threadIdx.x;
  const int lane = t & 63;
  const int wv   = t >> 6;
  const int q    = lane >> 4;     // k-quarter within frag
  const int c    = lane & 15;
  const int nb0  = blockIdx.x << 6;

  // stage Wt: lds_wt[k][d] = bf16(W[d][k]); coalesced global reads
  #pragma unroll 8
  for (int i = 0; i < 64; ++i) {
    int idx = (i << 8) + t;       // = d*64 + k
    lds_wt[(idx & 63) * 264 + (idx >> 6)] = f2bf(Wm[idx]);
  }

  // A-frags from global, converted to bf16, resident across N-tiles
  const int arow = nb0 + (wv << 4) + c;
  const float* xrow = x + (size_t)arow * DD + (q << 3);
  u16x8 afr[8];
  #pragma unroll
  for (int kb = 0; kb < 8; ++kb) {
    float4 u0 = *(const float4*)(xrow + kb * 32);
    float4 u1 = *(const float4*)(xrow + kb * 32 + 4);
    u16x8 af;
    af[0] = f2bf(u0.x); af[1] = f2bf(u0.y); af[2] = f2bf(u0.z); af[3] = f2bf(u0.w);
    af[4] = f2bf(u1.x); af[5] = f2bf(u1.y); af[6] = f2bf(u1.z); af[7] = f2bf(u1.w);
    afr[kb] = af;
  }
  __syncthreads();

  f32x4 acc[4];
  #pragma unroll
  for (int n = 0; n < 4; ++n) acc[n] = (f32x4){0.f, 0.f, 0.f, 0.f};
  #pragma unroll
  for (int n = 0; n < 4; ++n) {
    #pragma unroll
    for (int kb = 0; kb < 8; ++kb) {
      u16x8 bu = *(const u16x8*)(&lds_wt[(n * 16 + c) * 264 + kb * 32 + (q << 3)]);
      acc[n] = __builtin_amdgcn_mfma_f32_16x16x32_bf16(
          __builtin_bit_cast(bf16x8, afr[kb]),
          __builtin_bit_cast(bf16x8, bu), acc[n], 0, 0, 0);
    }
  }

  // epilogue: z = logits + b + gumbel; per-row argmax/softmax
  float bb[4];
  #pragma unroll
  for (int n = 0; n < 4; ++n) bb[n] = bvec[n * 16 + c];
  const int nodeq = nb0 + (wv << 4) + (q << 2);   // rows q*4..q*4+3
  float ent = 0.f;
  #pragma unroll
  for (int reg = 0; reg < 4; ++reg) {
    float zz[4];
    #pragma unroll
    for (int n = 0; n < 4; ++n)
      zz[n] = acc[n][reg] + bb[n] + gum[(size_t)(nodeq + reg) * KK + n * 16 + c];
    float m = zz[0]; int a = c;
    #pragma unroll
    for (int n = 1; n < 4; ++n)
      if (zz[n] > m) { m = zz[n]; a = n * 16 + c; }   // strict >: first max
    #pragma unroll
    for (int mask = 1; mask <= 8; mask <<= 1) {
      float mo = __shfl_xor(m, mask, 64);
      int   ao = __shfl_xor(a, mask, 64);
      if (mo > m || (mo == m && ao < a)) { m = mo; a = ao; }  // ties -> lower k
    }
    float ls = 0.f;
    #pragma unroll
    for (int n = 0; n < 4; ++n) ls += expf(zz[n] - m);
    #pragma unroll
    for (int mask = 1; mask <= 8; mask <<= 1) ls += __shfl_xor(ls, mask, 64);
    if (c == 0) {
      int node = nodeq + reg;
      float p  = 1.0f / ls;                 // softmax value at argmax
      float s1 = (1.0f - p) + p;            // straight-through value (≈1)
      assign[node] = a;
      s1g[node]    = s1;
      atomicAdd(&c_acc[((node >> 10) << 6) + a], s1 * s1);
      ent += -s1 * logf(s1 + 1e-15f);       // non-argmax terms are exactly 0
    }
  }
  #pragma unroll
  for (int off = 32; off; off >>= 1) ent += __shfl_down(ent, off, 64);
  if (lane == 0) esum[wv] = ent;
  __syncthreads();
  if (t == 0) atomicAdd(ent_acc, esum[0] + esum[1] + esum[2] + esum[3]);
}

// ---------------------------------------------------------------------------
// Kernel 2a: per-graph counting sort of nodes by cluster.
// 64 blocks (one per graph) x 256 threads x 4 nodes.
// ---------------------------------------------------------------------------
__global__ __launch_bounds__(256) void sort_kernel(
    const int* __restrict__ assign, int* __restrict__ sorted,
    int* __restrict__ goff)
{
  __shared__ int hist[64];
  __shared__ int offs[65];
  __shared__ int cursor[64];
  const int t = threadIdx.x;
  const int g = blockIdx.x;
  const int n0 = g << 10;
  if (t < 64) hist[t] = 0;
  __syncthreads();
  int4 av = ((const int4*)(assign + n0))[t];   // nodes t*4 .. t*4+3
  atomicAdd(&hist[av.x], 1);
  atomicAdd(&hist[av.y], 1);
  atomicAdd(&hist[av.z], 1);
  atomicAdd(&hist[av.w], 1);
  __syncthreads();
  if (t == 0) {
    int s = 0;
    #pragma unroll
    for (int k = 0; k < 64; ++k) { offs[k] = s; s += hist[k]; }
    offs[64] = s;   // = 1024
  }
  __syncthreads();
  if (t < 64) cursor[t] = offs[t];
  if (t < 65) goff[g * 65 + t] = offs[t];
  __syncthreads();
  int p;
  p = atomicAdd(&cursor[av.x], 1); sorted[n0 + p] = n0 + t * 4 + 0;
  p = atomicAdd(&cursor[av.y], 1); sorted[n0 + p] = n0 + t * 4 + 1;
  p = atomicAdd(&cursor[av.z], 1); sorted[n0 + p] = n0 + t * 4 + 2;
  p = atomicAdd(&cursor[av.w], 1); sorted[n0 + p] = n0 + t * 4 + 3;
}

// ---------------------------------------------------------------------------
// Kernel 2b: pooled features via dense gather.
// 4096 blocks = (graph g, cluster k) x 256 threads (one output dim each).
// ---------------------------------------------------------------------------
__global__ __launch_bounds__(256, 8) void gather_kernel(
    const float* __restrict__ x, const float* __restrict__ s1,
    const int* __restrict__ sorted, const int* __restrict__ goff,
    float* __restrict__ out)
{
  const int t = threadIdx.x;
  const int g = blockIdx.x >> 6;
  const int k = blockIdx.x & 63;
  const int o0 = goff[g * 65 + k];
  const int o1 = goff[g * 65 + k + 1];
  const int* sp = sorted + (g << 10);
  float sum = 0.f;
  int i = o0;
  for (; i + 4 <= o1; i += 4) {
    int n0 = sp[i], n1 = sp[i + 1], n2 = sp[i + 2], n3 = sp[i + 3];
    float w0 = s1[n0], w1 = s1[n1], w2 = s1[n2], w3 = s1[n3];
    float x0 = x[(size_t)n0 * DD + t];
    float x1 = x[(size_t)n1 * DD + t];
    float x2 = x[(size_t)n2 * DD + t];
    float x3 = x[(size_t)n3 * DD + t];
    sum += w0 * x0 + w1 * x1 + w2 * x2 + w3 * x3;
  }
  for (; i < o1; ++i) {
    int n = sp[i];
    sum += s1[n] * x[(size_t)n * DD + t];
  }
  out[((size_t)(g * 64 + k)) * DD + t] = sum;
}

// ---------------------------------------------------------------------------
// Kernel 3: edges -> per-block LDS adjacency, plain-stored partials in ws.
// 256 blocks (4 per graph) x 1024 threads x 4 edges.
// ---------------------------------------------------------------------------
__global__ __launch_bounds__(1024, 2) void edge_kernel(
    const int* __restrict__ src, const int* __restrict__ dst,
    const float* __restrict__ ew, const int* __restrict__ assign,
    const float* __restrict__ s1, float* __restrict__ adj_partial,
    float* __restrict__ sqA, float* __restrict__ crossA)
{
  __shared__ float adj[4096];           // 64x64 pooled adjacency (partial)
  const int t   = threadIdx.x;
  const int blk = blockIdx.x;
  const int g   = blk >> 2;
  #pragma unroll
  for (int i = 0; i < 4; ++i) adj[i * 1024 + t] = 0.f;
  __syncthreads();
  const int e0 = (g << 14) + ((blk & 3) << 12);   // 4096 edges per block
  float sq = 0.f, cr = 0.f;
  #pragma unroll
  for (int i = 0; i < 4; ++i) {
    int e = e0 + i * 1024 + t;
    int u = src[e], v = dst[e];
    float w = ew[e];
    int au = assign[u], av = assign[v];
    float contrib = w * s1[u] * s1[v];
    atomicAdd(&adj[au * 64 + av], contrib);   // ds_add_f32
    sq += w * w;
    if (au == av) cr += contrib;
  }
  #pragma unroll
  for (int off = 32; off; off >>= 1) {
    sq += __shfl_down(sq, off, 64);
    cr += __shfl_down(cr, off, 64);
  }
  if ((t & 63) == 0) {
    atomicAdd(&sqA[g], sq);
    atomicAdd(&crossA[g], cr);
  }
  __syncthreads();
  float* pp = adj_partial + (size_t)blk * 4096;
  #pragma unroll
  for (int i = 0; i < 4; ++i) pp[i * 1024 + t] = adj[i * 1024 + t];
}

// Combine 4 partials per graph -> out_adj (plain stores, fully overwrites).
__global__ __launch_bounds__(1024) void adj_combine_kernel(
    const float* __restrict__ adj_partial, float* __restrict__ out_adj)
{
  int idx = blockIdx.x * 1024 + threadIdx.x;   // 262144 cells
  int g = idx >> 12;
  int cell = idx & 4095;
  const float* p = adj_partial + ((size_t)(g * 4)) * 4096 + cell;
  out_adj[idx] = p[0] + p[4096] + p[8192] + p[12288];
}

// Fallback (small ws): global-atomic combine, needs out_adj pre-zeroed.
__global__ __launch_bounds__(1024, 2) void edge_kernel_atomic(
    const int* __restrict__ src, const int* __restrict__ dst,
    const float* __restrict__ ew, const int* __restrict__ assign,
    const float* __restrict__ s1, float* __restrict__ out_adj,
    float* __restrict__ sqA, float* __restrict__ crossA)
{
  __shared__ float adj[4096];
  const int t   = threadIdx.x;
  const int blk = blockIdx.x;
  const int g   = blk >> 2;
  #pragma unroll
  for (int i = 0; i < 4; ++i) adj[i * 1024 + t] = 0.f;
  __syncthreads();
  const int e0 = (g << 14) + ((blk & 3) << 12);
  float sq = 0.f, cr = 0.f;
  #pragma unroll
  for (int i = 0; i < 4; ++i) {
    int e = e0 + i * 1024 + t;
    int u = src[e], v = dst[e];
    float w = ew[e];
    int au = assign[u], av = assign[v];
    float contrib = w * s1[u] * s1[v];
    atomicAdd(&adj[au * 64 + av], contrib);
    sq += w * w;
    if (au == av) cr += contrib;
  }
  #pragma unroll
  for (int off = 32; off; off >>= 1) {
    sq += __shfl_down(sq, off, 64);
    cr += __shfl_down(cr, off, 64);
  }
  if ((t & 63) == 0) {
    atomicAdd(&sqA[g], sq);
    atomicAdd(&crossA[g], cr);
  }
  __syncthreads();
  float* adjg = out_adj + (size_t)g * 4096;
  #pragma unroll
  for (int i = 0; i < 4; ++i)
    atomicAdd(&adjg[i * 1024 + t], adj[i * 1024 + t]);
}

// ---------------------------------------------------------------------------
// Kernel 4: link/entropy scalars + batch / batch_ptr tails.
// ---------------------------------------------------------------------------
__global__ __launch_bounds__(256) void finalize_kernel(
    const float* __restrict__ c, const float* __restrict__ sqA,
    const float* __restrict__ crossA, const float* __restrict__ ent_acc,
    float* __restrict__ out)
{
  const int t = threadIdx.x;
  float link = 0.f;
  if (t < 64) {
    const float* cg = c + t * 64;
    float ssq = 0.f;
    #pragma unroll
    for (int k = 0; k < 64; ++k) ssq += cg[k] * cg[k];
    float val = sqA[t] - 2.0f * crossA[t] + ssq;
    link = sqrtf(fmaxf(val, 0.f)) / 16384.0f;   // e_per = 16384
  }
  #pragma unroll
  for (int off = 32; off; off >>= 1) link += __shfl_down(link, off, 64);
  if (t == 0) {
    out[LINK_OFF] = link / 64.0f;
    out[ENT_OFF]  = ent_acc[0] / (float)NN;
  }
  for (int r = t; r < 4096; r += 256) out[BATCH_OFF + r] = (float)(r >> 6);
  for (int i = t; i < 65; i += 256)   out[BPTR_OFF + i]  = (float)(i << 6);
}

extern "C" void kernel_launch(void* const* d_in, const int* in_sizes, int n_in,
                              void* d_out, int out_size, void* d_ws, size_t ws_size,
                              hipStream_t stream) {
  const float* x    = (const float*)d_in[0];
  const float* ew   = (const float*)d_in[1];
  const float* Wm   = (const float*)d_in[2];
  const float* bvec = (const float*)d_in[3];
  const float* gum  = (const float*)d_in[4];
  const int*   eidx = (const int*)d_in[5];
  float* out = (float*)d_out;
  char*  ws  = (char*)d_ws;

  int*   assign = (int*)(ws + WS_ASSIGN);
  float* s1     = (float*)(ws + WS_S1);
  float* c      = (float*)(ws + WS_C);
  float* sqA    = (float*)(ws + WS_SQA);
  float* crossA = (float*)(ws + WS_CROSS);
  float* entacc = (float*)(ws + WS_ENT);
  int*   sorted = (int*)(ws + WS_SORT);
  int*   goff   = (int*)(ws + WS_GOFF);
  float* adjp   = (float*)(ws + WS_ADJP);

  const int E = in_sizes[1];   // 1048576

  // zero the small atomic accumulators (c, sqA, crossA, ent)
  hipMemsetAsync(ws + WS_C, 0, (WS_ENT + 4) - WS_C, stream);

  pool_assign_kernel<<<1024, 256, 0, stream>>>(x, Wm, bvec, gum, assign, s1, c, entacc);
  sort_kernel<<<64, 256, 0, stream>>>(assign, sorted, goff);
  gather_kernel<<<4096, 256, 0, stream>>>(x, s1, sorted, goff, out + OUT_OFF);
  if (ws_size >= (size_t)WS_NEED) {
    edge_kernel<<<256, 1024, 0, stream>>>(eidx, eidx + E, ew, assign, s1,
                                          adjp, sqA, crossA);
    adj_combine_kernel<<<256, 1024, 0, stream>>>(adjp, out + ADJ_OFF);
  } else {
    hipMemsetAsync(out + ADJ_OFF, 0, (size_t)64 * 4096 * 4, stream);
    edge_kernel_atomic<<<256, 1024, 0, stream>>>(eidx, eidx + E, ew, assign, s1,
                                                 out + ADJ_OFF, sqA, crossA);
  }
  finalize_kernel<<<1, 256, 0, stream>>>(c, sqA, crossA, entacc, out);
}

// Round 8
// 60.366 us; speedup vs baseline: 1.9713x; 1.5230x over previous
//
#include <hip/hip_runtime.h>

// Problem constants (StochPool: B=64, N_PER=1024, D=256, K=64, DEG=16)
#define NN 65536           // total nodes
#define DD 256             // feature dim
#define KK 64              // pools per graph
#define NPG 1024           // nodes per graph

// d_out layout (flat float32, outputs concatenated in return order)
#define OUT_OFF   0          // (4096, 256)
#define ADJ_OFF   1048576    // (64, 64, 64)
#define LINK_OFF  1310720    // scalar
#define ENT_OFF   1310721    // scalar
#define BATCH_OFF 1310722    // (4096,) as float
#define BPTR_OFF  1314818    // (65,) as float

// ws layout (bytes) — NOTHING here needs pre-zeroing (all plain stores)
#define WS_ASSIGN 0          // int32 x 65536
#define WS_S1     262144     // float x 65536
#define WS_C      524288     // float x 4096   (StS diagonal, by sort_kernel)
#define WS_SQP    540672     // float x 256    (per-edge-block sum(w^2) partials)
#define WS_CRP    541696     // float x 256    (per-edge-block cross partials)
#define WS_ENTP   542720     // float x 1024   (per-pool-block entropy partials)
#define WS_SORT   1048576    // int32 x 65536 (node ids sorted by cluster, per graph)
#define WS_GOFF   1310720    // int32 x 64*65 (per-graph bin offsets)
#define WS_ADJP   1331200    // float x 256*4096 (per-block adjacency partials, 4 MB)
#define WS_NEED   (WS_ADJP + 256 * 4096 * 4)

typedef __bf16 bf16x8 __attribute__((ext_vector_type(8)));
typedef unsigned short u16x8 __attribute__((ext_vector_type(8)));
typedef float f32x4 __attribute__((ext_vector_type(4)));

// f32 -> bf16 with round-to-nearest-even
static __device__ __forceinline__ unsigned short f2bf(float f) {
  unsigned int u = __float_as_uint(f);
  return (unsigned short)((u + 0x7fffu + ((u >> 16) & 1u)) >> 16);
}

// ---------------------------------------------------------------------------
// Kernel 1: logits GEMM via bf16 MFMA + in-register argmax/softmax.
// 1024 blocks x 256 threads (4 waves); block owns 64 consecutive nodes,
// wave wv owns nodes [nb0+16*wv, +16). Per wave: 4 N-tiles of
// mfma_f32_16x16x32_bf16 x 8 K-steps (K=256).
// Entropy: per-block partial plain-stored to entp[blockIdx] (no atomics).
// ---------------------------------------------------------------------------
__global__ __launch_bounds__(256, 4) void pool_assign_kernel(
    const float* __restrict__ x, const float* __restrict__ Wm,
    const float* __restrict__ bvec, const float* __restrict__ gum,
    int* __restrict__ assign, float* __restrict__ s1g,
    float* __restrict__ entp)
{
  __shared__ unsigned short lds_wt[64 * 264];   // Wt[k][d] bf16, 33 KB
  __shared__ float esum[4];
  const int t    = threadIdx.x;
  const int lane = t & 63;
  const int wv   = t >> 6;
  const int q    = lane >> 4;     // k-quarter within frag
  const int c    = lane & 15;
  const int nb0  = blockIdx.x << 6;

  // stage Wt: lds_wt[k][d] = bf16(W[d][k]); coalesced global reads
  #pragma unroll 8
  for (int i = 0; i < 64; ++i) {
    int idx = (i << 8) + t;       // = d*64 + k
    lds_wt[(idx & 63) * 264 + (idx >> 6)] = f2bf(Wm[idx]);
  }

  // A-frags from global, converted to bf16, resident across N-tiles
  const int arow = nb0 + (wv << 4) + c;
  const float* xrow = x + (size_t)arow * DD + (q << 3);
  u16x8 afr[8];
  #pragma unroll
  for (int kb = 0; kb < 8; ++kb) {
    float4 u0 = *(const float4*)(xrow + kb * 32);
    float4 u1 = *(const float4*)(xrow + kb * 32 + 4);
    u16x8 af;
    af[0] = f2bf(u0.x); af[1] = f2bf(u0.y); af[2] = f2bf(u0.z); af[3] = f2bf(u0.w);
    af[4] = f2bf(u1.x); af[5] = f2bf(u1.y); af[6] = f2bf(u1.z); af[7] = f2bf(u1.w);
    afr[kb] = af;
  }
  __syncthreads();

  f32x4 acc[4];
  #pragma unroll
  for (int n = 0; n < 4; ++n) acc[n] = (f32x4){0.f, 0.f, 0.f, 0.f};
  #pragma unroll
  for (int n = 0; n < 4; ++n) {
    #pragma unroll
    for (int kb = 0; kb < 8; ++kb) {
      u16x8 bu = *(const u16x8*)(&lds_wt[(n * 16 + c) * 264 + kb * 32 + (q << 3)]);
      acc[n] = __builtin_amdgcn_mfma_f32_16x16x32_bf16(
          __builtin_bit_cast(bf16x8, afr[kb]),
          __builtin_bit_cast(bf16x8, bu), acc[n], 0, 0, 0);
    }
  }

  // epilogue: z = logits + b + gumbel; per-row argmax/softmax
  float bb[4];
  #pragma unroll
  for (int n = 0; n < 4; ++n) bb[n] = bvec[n * 16 + c];
  const int nodeq = nb0 + (wv << 4) + (q << 2);   // rows q*4..q*4+3
  float ent = 0.f;
  #pragma unroll
  for (int reg = 0; reg < 4; ++reg) {
    float zz[4];
    #pragma unroll
    for (int n = 0; n < 4; ++n)
      zz[n] = acc[n][reg] + bb[n] + gum[(size_t)(nodeq + reg) * KK + n * 16 + c];
    float m = zz[0]; int a = c;
    #pragma unroll
    for (int n = 1; n < 4; ++n)
      if (zz[n] > m) { m = zz[n]; a = n * 16 + c; }   // strict >: first max
    #pragma unroll
    for (int mask = 1; mask <= 8; mask <<= 1) {
      float mo = __shfl_xor(m, mask, 64);
      int   ao = __shfl_xor(a, mask, 64);
      if (mo > m || (mo == m && ao < a)) { m = mo; a = ao; }  // ties -> lower k
    }
    float ls = 0.f;
    #pragma unroll
    for (int n = 0; n < 4; ++n) ls += expf(zz[n] - m);
    #pragma unroll
    for (int mask = 1; mask <= 8; mask <<= 1) ls += __shfl_xor(ls, mask, 64);
    if (c == 0) {
      int node = nodeq + reg;
      float p  = 1.0f / ls;                 // softmax value at argmax
      float s1 = (1.0f - p) + p;            // straight-through value (≈1)
      assign[node] = a;
      s1g[node]    = s1;
      ent += -s1 * logf(s1 + 1e-15f);       // non-argmax terms are exactly 0
    }
  }
  #pragma unroll
  for (int off = 32; off; off >>= 1) ent += __shfl_down(ent, off, 64);
  if (lane == 0) esum[wv] = ent;
  __syncthreads();
  if (t == 0) entp[blockIdx.x] = esum[0] + esum[1] + esum[2] + esum[3];
}

// ---------------------------------------------------------------------------
// Kernel 2a: per-graph counting sort of nodes by cluster + StS diagonal.
// 64 blocks (one per graph) x 256 threads x 4 nodes.
// c[g][k] = sum of s1^2 over bin members (plain store, no pre-zero needed).
// ---------------------------------------------------------------------------
__global__ __launch_bounds__(256) void sort_kernel(
    const int* __restrict__ assign, const float* __restrict__ s1,
    int* __restrict__ sorted, int* __restrict__ goff,
    float* __restrict__ c_out)
{
  __shared__ int hist[64];
  __shared__ int offs[65];
  __shared__ int cursor[64];
  const int t = threadIdx.x;
  const int g = blockIdx.x;
  const int n0 = g << 10;
  if (t < 64) hist[t] = 0;
  __syncthreads();
  int4 av = ((const int4*)(assign + n0))[t];   // nodes t*4 .. t*4+3
  atomicAdd(&hist[av.x], 1);
  atomicAdd(&hist[av.y], 1);
  atomicAdd(&hist[av.z], 1);
  atomicAdd(&hist[av.w], 1);
  __syncthreads();
  if (t == 0) {
    int s = 0;
    #pragma unroll
    for (int k = 0; k < 64; ++k) { offs[k] = s; s += hist[k]; }
    offs[64] = s;   // = 1024
  }
  __syncthreads();
  if (t < 64) cursor[t] = offs[t];
  if (t < 65) goff[g * 65 + t] = offs[t];
  __syncthreads();
  int p;
  p = atomicAdd(&cursor[av.x], 1); sorted[n0 + p] = n0 + t * 4 + 0;
  p = atomicAdd(&cursor[av.y], 1); sorted[n0 + p] = n0 + t * 4 + 1;
  p = atomicAdd(&cursor[av.z], 1); sorted[n0 + p] = n0 + t * 4 + 2;
  p = atomicAdd(&cursor[av.w], 1); sorted[n0 + p] = n0 + t * 4 + 3;
  __syncthreads();
  if (t < 64) {
    float cs = 0.f;
    int e = offs[t + 1];
    for (int o = offs[t]; o < e; ++o) {
      float v = s1[sorted[n0 + o]];
      cs += v * v;
    }
    c_out[(g << 6) + t] = cs;
  }
}

// ---------------------------------------------------------------------------
// Kernel 2b: pooled features via dense gather.
// 4096 blocks = (graph g, cluster k) x 256 threads (one output dim each).
// ---------------------------------------------------------------------------
__global__ __launch_bounds__(256, 8) void gather_kernel(
    const float* __restrict__ x, const float* __restrict__ s1,
    const int* __restrict__ sorted, const int* __restrict__ goff,
    float* __restrict__ out)
{
  const int t = threadIdx.x;
  const int g = blockIdx.x >> 6;
  const int k = blockIdx.x & 63;
  const int o0 = goff[g * 65 + k];
  const int o1 = goff[g * 65 + k + 1];
  const int* sp = sorted + (g << 10);
  float sum = 0.f;
  int i = o0;
  for (; i + 4 <= o1; i += 4) {
    int n0 = sp[i], n1 = sp[i + 1], n2 = sp[i + 2], n3 = sp[i + 3];
    float w0 = s1[n0], w1 = s1[n1], w2 = s1[n2], w3 = s1[n3];
    float x0 = x[(size_t)n0 * DD + t];
    float x1 = x[(size_t)n1 * DD + t];
    float x2 = x[(size_t)n2 * DD + t];
    float x3 = x[(size_t)n3 * DD + t];
    sum += w0 * x0 + w1 * x1 + w2 * x2 + w3 * x3;
  }
  for (; i < o1; ++i) {
    int n = sp[i];
    sum += s1[n] * x[(size_t)n * DD + t];
  }
  out[((size_t)(g * 64 + k)) * DD + t] = sum;
}

// ---------------------------------------------------------------------------
// Kernel 3: edges -> per-block LDS adjacency, plain-stored partials in ws.
// 256 blocks (4 per graph) x 1024 threads x 4 edges. sq/cr partials are
// block-reduced and plain-stored (no global atomics anywhere).
// ---------------------------------------------------------------------------
__global__ __launch_bounds__(1024, 2) void edge_kernel(
    const int* __restrict__ src, const int* __restrict__ dst,
    const float* __restrict__ ew, const int* __restrict__ assign,
    const float* __restrict__ s1, float* __restrict__ adj_partial,
    float* __restrict__ sqP, float* __restrict__ crP)
{
  __shared__ float adj[4096];           // 64x64 pooled adjacency (partial)
  __shared__ float redsq[16], redcr[16];
  const int t   = threadIdx.x;
  const int blk = blockIdx.x;
  const int g   = blk >> 2;
  #pragma unroll
  for (int i = 0; i < 4; ++i) adj[i * 1024 + t] = 0.f;
  __syncthreads();
  const int e0 = (g << 14) + ((blk & 3) << 12);   // 4096 edges per block
  float sq = 0.f, cr = 0.f;
  #pragma unroll
  for (int i = 0; i < 4; ++i) {
    int e = e0 + i * 1024 + t;
    int u = src[e], v = dst[e];
    float w = ew[e];
    int au = assign[u], av = assign[v];
    float contrib = w * s1[u] * s1[v];
    atomicAdd(&adj[au * 64 + av], contrib);   // ds_add_f32
    sq += w * w;
    if (au == av) cr += contrib;
  }
  #pragma unroll
  for (int off = 32; off; off >>= 1) {
    sq += __shfl_down(sq, off, 64);
    cr += __shfl_down(cr, off, 64);
  }
  if ((t & 63) == 0) { redsq[t >> 6] = sq; redcr[t >> 6] = cr; }
  __syncthreads();
  if (t == 0) {
    float a = 0.f, b2 = 0.f;
    #pragma unroll
    for (int i = 0; i < 16; ++i) { a += redsq[i]; b2 += redcr[i]; }
    sqP[blk] = a;
    crP[blk] = b2;
  }
  float* pp = adj_partial + (size_t)blk * 4096;
  #pragma unroll
  for (int i = 0; i < 4; ++i) pp[i * 1024 + t] = adj[i * 1024 + t];
}

// Combine 4 partials per graph -> out_adj (plain stores, fully overwrites).
__global__ __launch_bounds__(1024) void adj_combine_kernel(
    const float* __restrict__ adj_partial, float* __restrict__ out_adj)
{
  int idx = blockIdx.x * 1024 + threadIdx.x;   // 262144 cells
  int g = idx >> 12;
  int cell = idx & 4095;
  const float* p = adj_partial + ((size_t)(g * 4)) * 4096 + cell;
  out_adj[idx] = p[0] + p[4096] + p[8192] + p[12288];
}

// Fallback (small ws): global-atomic combine, needs out_adj pre-zeroed.
__global__ __launch_bounds__(1024, 2) void edge_kernel_atomic(
    const int* __restrict__ src, const int* __restrict__ dst,
    const float* __restrict__ ew, const int* __restrict__ assign,
    const float* __restrict__ s1, float* __restrict__ out_adj,
    float* __restrict__ sqP, float* __restrict__ crP)
{
  __shared__ float adj[4096];
  __shared__ float redsq[16], redcr[16];
  const int t   = threadIdx.x;
  const int blk = blockIdx.x;
  const int g   = blk >> 2;
  #pragma unroll
  for (int i = 0; i < 4; ++i) adj[i * 1024 + t] = 0.f;
  __syncthreads();
  const int e0 = (g << 14) + ((blk & 3) << 12);
  float sq = 0.f, cr = 0.f;
  #pragma unroll
  for (int i = 0; i < 4; ++i) {
    int e = e0 + i * 1024 + t;
    int u = src[e], v = dst[e];
    float w = ew[e];
    int au = assign[u], av = assign[v];
    float contrib = w * s1[u] * s1[v];
    atomicAdd(&adj[au * 64 + av], contrib);
    sq += w * w;
    if (au == av) cr += contrib;
  }
  #pragma unroll
  for (int off = 32; off; off >>= 1) {
    sq += __shfl_down(sq, off, 64);
    cr += __shfl_down(cr, off, 64);
  }
  if ((t & 63) == 0) { redsq[t >> 6] = sq; redcr[t >> 6] = cr; }
  __syncthreads();
  if (t == 0) {
    float a = 0.f, b2 = 0.f;
    #pragma unroll
    for (int i = 0; i < 16; ++i) { a += redsq[i]; b2 += redcr[i]; }
    sqP[blk] = a;
    crP[blk] = b2;
  }
  float* adjg = out_adj + (size_t)g * 4096;
  #pragma unroll
  for (int i = 0; i < 4; ++i)
    atomicAdd(&adjg[i * 1024 + t], adj[i * 1024 + t]);
}

// ---------------------------------------------------------------------------
// Kernel 4: link/entropy scalars + batch / batch_ptr tails.
// ---------------------------------------------------------------------------
__global__ __launch_bounds__(256) void finalize_kernel(
    const float* __restrict__ c, const float* __restrict__ sqP,
    const float* __restrict__ crP, const float* __restrict__ entp,
    float* __restrict__ out)
{
  __shared__ float esum2[4];
  const int t = threadIdx.x;
  float link = 0.f;
  if (t < 64) {
    const float* cg = c + t * 64;
    float ssq = 0.f;
    #pragma unroll
    for (int k = 0; k < 64; ++k) ssq += cg[k] * cg[k];
    float sq = sqP[4 * t] + sqP[4 * t + 1] + sqP[4 * t + 2] + sqP[4 * t + 3];
    float cr = crP[4 * t] + crP[4 * t + 1] + crP[4 * t + 2] + crP[4 * t + 3];
    float val = sq - 2.0f * cr + ssq;
    link = sqrtf(fmaxf(val, 0.f)) / 16384.0f;   // e_per = 16384
  }
  #pragma unroll
  for (int off = 32; off; off >>= 1) link += __shfl_down(link, off, 64);
  // entropy: reduce 1024 per-block partials
  float ent = entp[t] + entp[t + 256] + entp[t + 512] + entp[t + 768];
  #pragma unroll
  for (int off = 32; off; off >>= 1) ent += __shfl_down(ent, off, 64);
  if ((t & 63) == 0) esum2[t >> 6] = ent;
  __syncthreads();
  if (t == 0) {
    out[LINK_OFF] = link / 64.0f;
    out[ENT_OFF]  = (esum2[0] + esum2[1] + esum2[2] + esum2[3]) / (float)NN;
  }
  for (int r = t; r < 4096; r += 256) out[BATCH_OFF + r] = (float)(r >> 6);
  for (int i = t; i < 65; i += 256)   out[BPTR_OFF + i]  = (float)(i << 6);
}

extern "C" void kernel_launch(void* const* d_in, const int* in_sizes, int n_in,
                              void* d_out, int out_size, void* d_ws, size_t ws_size,
                              hipStream_t stream) {
  const float* x    = (const float*)d_in[0];
  const float* ew   = (const float*)d_in[1];
  const float* Wm   = (const float*)d_in[2];
  const float* bvec = (const float*)d_in[3];
  const float* gum  = (const float*)d_in[4];
  const int*   eidx = (const int*)d_in[5];
  float* out = (float*)d_out;
  char*  ws  = (char*)d_ws;

  int*   assign = (int*)(ws + WS_ASSIGN);
  float* s1     = (float*)(ws + WS_S1);
  float* c      = (float*)(ws + WS_C);
  float* sqP    = (float*)(ws + WS_SQP);
  float* crP    = (float*)(ws + WS_CRP);
  float* entp   = (float*)(ws + WS_ENTP);
  int*   sorted = (int*)(ws + WS_SORT);
  int*   goff   = (int*)(ws + WS_GOFF);
  float* adjp   = (float*)(ws + WS_ADJP);

  const int E = in_sizes[1];   // 1048576

  pool_assign_kernel<<<1024, 256, 0, stream>>>(x, Wm, bvec, gum, assign, s1, entp);
  sort_kernel<<<64, 256, 0, stream>>>(assign, s1, sorted, goff, c);
  gather_kernel<<<4096, 256, 0, stream>>>(x, s1, sorted, goff, out + OUT_OFF);
  if (ws_size >= (size_t)WS_NEED) {
    edge_kernel<<<256, 1024, 0, stream>>>(eidx, eidx + E, ew, assign, s1,
                                          adjp, sqP, crP);
    adj_combine_kernel<<<256, 1024, 0, stream>>>(adjp, out + ADJ_OFF);
  } else {
    hipMemsetAsync(out + ADJ_OFF, 0, (size_t)64 * 4096 * 4, stream);
    edge_kernel_atomic<<<256, 1024, 0, stream>>>(eidx, eidx + E, ew, assign, s1,
                                                 out + ADJ_OFF, sqP, crP);
  }
  finalize_kernel<<<1, 256, 0, stream>>>(c, sqP, crP, entp, out);
}